// Round 1
// baseline (377.155 us; speedup 1.0000x reference)
//
#include <hip/hip_runtime.h>
#include <math.h>

#define EPS 1e-5f

__device__ __forceinline__ float gelu_exact(float x) {
    return 0.5f * x * (1.0f + erff(x * 0.7071067811865476f));
}

// ---- block reductions for finalize (192 threads = 3 waves) ----
__device__ float block_sum(float v, float* red) {
    int lane = threadIdx.x & 63, wid = threadIdx.x >> 6;
#pragma unroll
    for (int off = 32; off > 0; off >>= 1) v += __shfl_down(v, off, 64);
    if (lane == 0) red[wid] = v;
    __syncthreads();
    int nw = ((int)blockDim.x + 63) >> 6;
    float s = red[0];
    for (int w = 1; w < nw; w++) s += red[w];
    __syncthreads();
    return s;
}

__device__ float block_max(float v, float* red) {
    int lane = threadIdx.x & 63, wid = threadIdx.x >> 6;
#pragma unroll
    for (int off = 32; off > 0; off >>= 1) v = fmaxf(v, __shfl_down(v, off, 64));
    if (lane == 0) red[wid] = v;
    __syncthreads();
    int nw = ((int)blockDim.x + 63) >> 6;
    float s = red[0];
    for (int w = 1; w < nw; w++) s = fmaxf(s, red[w]);
    __syncthreads();
    return s;
}

// ---- threefry2x32-20 (JAX PRNG), partitionable scheme (verified round 1) ----
__device__ void threefry2x32(unsigned k0, unsigned k1, unsigned x0, unsigned x1,
                             unsigned& o0, unsigned& o1) {
    unsigned ks[3] = {k0, k1, k0 ^ k1 ^ 0x1BD11BDAu};
    const unsigned rot[2][4] = {{13u, 15u, 26u, 6u}, {17u, 29u, 16u, 24u}};
    x0 += ks[0]; x1 += ks[1];
#pragma unroll
    for (int i = 0; i < 5; i++) {
#pragma unroll
        for (int j = 0; j < 4; j++) {
            unsigned r = rot[i & 1][j];
            x0 += x1;
            x1 = (x1 << r) | (x1 >> (32 - r));
            x1 ^= x0;
        }
        x0 += ks[(i + 1) % 3];
        x1 += ks[(i + 2) % 3] + (unsigned)(i + 1);
    }
    o0 = x0; o1 = x1;
}

__device__ float gumbel_at(int j) {
    unsigned o0, o1;
    threefry2x32(0u, 42u, 0u, (unsigned)j, o0, o1);
    unsigned bits = o0 ^ o1;
    float f = __uint_as_float((bits >> 9) | 0x3F800000u) - 1.0f;  // [0,1)
    float u = fmaxf(f + 1.17549435e-38f, 1.17549435e-38f);
    return -logf(-logf(u));
}

// ---- encode, wave-per-(b,l): 4 waves/block each own one l; wave-private
// LDS window (25 rows x 9 ch); H=128 InstanceNorm via in-wave shfl_xor
// butterflies (2 h per lane). Only 2 barriers, no cross-wave reductions. ----
__global__ __launch_bounds__(256) void encode_kernel(
    const float* __restrict__ x_lt, const float* __restrict__ x_st,
    const float* __restrict__ Ws, const float* __restrict__ bs,
    const float* __restrict__ Wt, const float* __restrict__ bt,
    float* __restrict__ e_lt, float* __restrict__ e_st) {
    const int b = blockIdx.y;
    const int w = threadIdx.x >> 6, ln = threadIdx.x & 63;
    const float* x; float* e; int L, l;
    if (blockIdx.x < 128) { x = x_lt; e = e_lt; L = 512; l = blockIdx.x * 4 + w; }
    else { x = x_st; e = e_st; L = 128; l = (blockIdx.x - 128) * 4 + w; }
    __shared__ float xw_all[4][228];   // 225 window values per wave
    __shared__ float sm_all[4][20];    // seas[0..8], mm[10..18] per wave
    float* xw = xw_all[w];
    float* sm = sm_all[w];
    const float* xb = x + (size_t)b * L * 9;
#pragma unroll
    for (int q = 0; q < 4; q++) {
        int f = ln + 64 * q;
        if (f < 225) {
            int row = f / 9, c = f - row * 9;
            int rr = l - 12 + row;
            rr = rr < 0 ? 0 : (rr >= L ? L - 1 : rr);
            xw[f] = xb[(size_t)rr * 9 + c];
        }
    }
    __syncthreads();
    if (ln < 9) {
        float s = 0.f;
#pragma unroll
        for (int j = 0; j < 25; j++) s += xw[j * 9 + ln];
        float x0 = xb[ln];                       // x[b][0][c]
        float mm = (s - 25.f * x0) * (1.0f / 25.0f);
        sm[ln] = (xw[108 + ln] - x0) - mm;       // seas: x[l]-x0 - (mm-x0)
        sm[ln + 10] = mm;                        // trend input
    }
    __syncthreads();
    // each lane owns h = ln and h = ln+64
    float ysA = bs[ln], ysB = bs[ln + 64];
    float ytA = bt[ln], ytB = bt[ln + 64];
#pragma unroll
    for (int c = 0; c < 9; c++) {
        float sv = sm[c], mv = sm[c + 10];
        ysA += sv * Ws[c * 128 + ln];
        ysB += sv * Ws[c * 128 + ln + 64];
        ytA += mv * Wt[c * 128 + ln];
        ytB += mv * Wt[c * 128 + ln + 64];
    }
    float sa = ysA + ysB, sb2 = ytA + ytB;
#pragma unroll
    for (int off = 32; off > 0; off >>= 1) {
        sa += __shfl_xor(sa, off, 64);
        sb2 += __shfl_xor(sb2, off, 64);
    }
    float ms = sa * (1.0f / 128.0f), mt = sb2 * (1.0f / 128.0f);
    float dA = ysA - ms, dB = ysB - ms;
    float tA = ytA - mt, tB = ytB - mt;
    float qa = dA * dA + dB * dB, qb = tA * tA + tB * tB;
#pragma unroll
    for (int off = 32; off > 0; off >>= 1) {
        qa += __shfl_xor(qa, off, 64);
        qb += __shfl_xor(qb, off, 64);
    }
    float inva = rsqrtf(qa * (1.0f / 128.0f) + EPS);
    float invb = rsqrtf(qb * (1.0f / 128.0f) + EPS);
    float* eo = e + ((size_t)b * L + l) * 128;
    eo[ln] = gelu_exact(dA * inva) + gelu_exact(tA * invb);
    eo[ln + 64] = gelu_exact(dB * inva) + gelu_exact(tB * invb);
}

// ---- wave-autonomous Linear -> InstanceNorm -> GELU, transposed-output.
// K-loop steps by 4: WR float4 A-reads (broadcast) from wave-private LDS +
// 4 float4 W loads, 16*WR FMAs per step. WR amortizes the per-wave W stream
// (W traffic = #waves * K*N*4B -> raise WR where the grid stays >= 1 blk/CU).
template <int K, int N, int WR, bool TRANS>
__global__ __launch_bounds__(256) void lbr_wave(
    const float* __restrict__ A, int S, int ABOFF,
    const float* __restrict__ W, const float* __restrict__ bias,
    float* __restrict__ out, int OROWS, int OBOFF) {
    constexpr int CG = N / 4;        // lanes covering the N dimension
    constexpr int SG = 64 / CG;      // row-subgroups per wave
    constexpr int RW = SG * WR;      // rows per wave
    constexpr int MT = 4 * RW;       // rows per block
    constexpr int LOG2MT = (MT == 8) ? 3 : ((MT == 16) ? 4 : 5);
    constexpr int STAGE = 4 * RW * K;
    constexpr int TILE = TRANS ? MT * (N + 4) : 0;
    constexpr int LSZ = STAGE > TILE ? STAGE : TILE;
    __shared__ __align__(16) float lds[LSZ];
    const int t = threadIdx.x;
    const int w = t >> 6, ln = t & 63;
    const int sg = ln / CG;
    const int n0 = (ln % CG) * 4;
    const int b = blockIdx.y;
    const int r0b = blockIdx.x * MT;
    const int r0w = r0b + w * RW;
    float* As = lds + w * RW * K;
    const float* Ab = A + (size_t)b * ABOFF;
    for (int idx = ln; idx < RW * (K / 4); idx += 64) {
        int rr = idx / (K / 4), kk = idx % (K / 4);
        float4 v = *(const float4*)(Ab + (size_t)(r0w + rr) * S + kk * 4);
        *(float4*)(As + rr * K + kk * 4) = v;
    }
    float4 acc[WR];
    {
        float4 bv = *(const float4*)(bias + n0);
#pragma unroll
        for (int j = 0; j < WR; j++) acc[j] = bv;
    }
    const float* ap = As + (sg * WR) * K;
    const float* wp = W + n0;
#pragma unroll 2
    for (int k = 0; k < K; k += 4) {
        float4 w0 = *(const float4*)(wp);
        float4 w1 = *(const float4*)(wp + N);
        float4 w2 = *(const float4*)(wp + 2 * N);
        float4 w3 = *(const float4*)(wp + 3 * N);
        wp += 4 * N;
#pragma unroll
        for (int j = 0; j < WR; j++) {
            float4 a4 = *(const float4*)(ap + j * K + k);
            acc[j].x += a4.x * w0.x; acc[j].y += a4.x * w0.y;
            acc[j].z += a4.x * w0.z; acc[j].w += a4.x * w0.w;
            acc[j].x += a4.y * w1.x; acc[j].y += a4.y * w1.y;
            acc[j].z += a4.y * w1.z; acc[j].w += a4.y * w1.w;
            acc[j].x += a4.z * w2.x; acc[j].y += a4.z * w2.y;
            acc[j].z += a4.z * w2.z; acc[j].w += a4.z * w2.w;
            acc[j].x += a4.w * w3.x; acc[j].y += a4.w * w3.y;
            acc[j].z += a4.w * w3.z; acc[j].w += a4.w * w3.w;
        }
    }
    float4 res[WR];
#pragma unroll
    for (int j = 0; j < WR; j++) {
        float s = acc[j].x + acc[j].y + acc[j].z + acc[j].w;
#pragma unroll
        for (int off = CG / 2; off > 0; off >>= 1) s += __shfl_xor(s, off, 64);
        float m = s * (1.0f / (float)N);
        float dx = acc[j].x - m, dy = acc[j].y - m, dz = acc[j].z - m, dw = acc[j].w - m;
        float q = dx * dx + dy * dy + dz * dz + dw * dw;
#pragma unroll
        for (int off = CG / 2; off > 0; off >>= 1) q += __shfl_xor(q, off, 64);
        float inv = rsqrtf(q * (1.0f / (float)N) + EPS);
        res[j].x = gelu_exact(dx * inv);
        res[j].y = gelu_exact(dy * inv);
        res[j].z = gelu_exact(dz * inv);
        res[j].w = gelu_exact(dw * inv);
    }
    if constexpr (TRANS) {
        __syncthreads();
#pragma unroll
        for (int j = 0; j < WR; j++) {
            int rl = w * RW + sg * WR + j;
            *(float4*)(lds + rl * (N + 4) + n0) = res[j];
        }
        __syncthreads();
        float* ob = out + (size_t)b * OBOFF + r0b;
        for (int e = t; e < MT * N; e += 256) {
            int r = e & (MT - 1), n = e >> LOG2MT;
            ob[(size_t)n * OROWS + r] = lds[r * (N + 4) + n];
        }
    } else {
        float* ob = out + (size_t)b * OBOFF;
#pragma unroll
        for (int j = 0; j < WR; j++) {
            int row = r0w + sg * WR + j;
            *(float4*)(ob + (size_t)row * N + n0) = res[j];
        }
    }
}

// ---- fused logits + gumbel-softmax(hard) selection. grid 32 (b), block 256. ----
__global__ __launch_bounds__(256) void logits_select(
    const float* __restrict__ O6, const float* __restrict__ Wr,
    const float* __restrict__ br, float* __restrict__ sel_w, int* __restrict__ sel_r) {
    int b = blockIdx.x, t = threadIdx.x;
    __shared__ float sO6[128 * 68];
    __shared__ float red[4][8];
    const float4* ob4 = (const float4*)(O6 + (size_t)b * 8192);
    for (int i4 = t; i4 < 2048; i4 += 256) {
        float4 v = ob4[i4];
        int p = i4 * 4;
        int h = p >> 6, l4 = p & 63;
        *(float4*)(&sO6[h * 68 + l4]) = v;
    }
    __syncthreads();
    float acc[8] = {0, 0, 0, 0, 0, 0, 0, 0};
#pragma unroll 4
    for (int q = 0; q < 32; q++) {
        int i = q * 256 + t;  // logits flat index: l4 = i>>7, h = i&127
        int l4 = i >> 7, h = i & 127;
        float v = sO6[h * 68 + l4];
        const float4* wr = (const float4*)(Wr + (size_t)i * 8);
        float4 w0 = wr[0], w1 = wr[1];
        acc[0] += v * w0.x; acc[1] += v * w0.y; acc[2] += v * w0.z; acc[3] += v * w0.w;
        acc[4] += v * w1.x; acc[5] += v * w1.y; acc[6] += v * w1.z; acc[7] += v * w1.w;
    }
#pragma unroll
    for (int j = 0; j < 8; j++)
#pragma unroll
        for (int off = 32; off > 0; off >>= 1) acc[j] += __shfl_xor(acc[j], off, 64);
    int lane = t & 63, wid = t >> 6;
    if (lane == 0)
        for (int j = 0; j < 8; j++) red[wid][j] = acc[j];
    __syncthreads();
    if (t == 0) {
        float z[8];
        for (int j = 0; j < 8; j++) {
            float lg = br[j] + red[0][j] + red[1][j] + red[2][j] + red[3][j];
            z[j] = lg + gumbel_at(b * 8 + j);
        }
        int am = 0;
        float zm = z[0];
        for (int j = 1; j < 8; j++)
            if (z[j] > zm) { zm = z[j]; am = j; }
        float ssum = 0.f;
        for (int j = 0; j < 8; j++) ssum += expf(z[j] - zm);
        float s = 1.0f / ssum;
        sel_w[b] = (1.0f - s) + s;
        sel_r[b] = am;
    }
}

// ---- regime-grouped einsum, 2 n-columns per block (16 accumulators) with
// float4 es reads: LDS:VALU issue ratio 192:128 per 4-h step (was 46:16/h).
// grid (64 n-pairs, 8 r), block 192 (t = m*3+o). ----
__global__ __launch_bounds__(192) void einsum_nsplit(
    const float* __restrict__ e_st, const float* __restrict__ proto,
    const int* __restrict__ sel_r, float* __restrict__ part) {
    const int n0 = blockIdx.x * 2, r = blockIdx.y, t = threadIdx.x;
    __shared__ int loc[32];
    __shared__ int s_gs;
    if (t == 0) {
        int g = 0;
        for (int bb = 0; bb < 32; bb++)
            if (sel_r[bb] == r) loc[g++] = bb;
        s_gs = g;
    }
    __syncthreads();
    const int gs = s_gs;
    if (gs == 0) return;
    __shared__ __align__(16) float es[2][8][128];
    const float* pb0 = proto + ((size_t)r * 128 + n0) * (128 * 192) + t;
    const float* pb1 = pb0 + 128 * 192;
    for (int s0 = 0; s0 < gs; s0 += 8) {
        int np = gs - s0 < 8 ? gs - s0 : 8;
        __syncthreads();
        for (int i4 = t; i4 < 512; i4 += 192) {
            int nn = i4 >> 8, rem = i4 & 255;
            int sb = rem >> 5, h4 = rem & 31;
            float4 v = make_float4(0.f, 0.f, 0.f, 0.f);
            if (sb < np) {
                int bb = loc[s0 + sb];
                v = ((const float4*)(e_st + ((size_t)bb * 128 + n0 + nn) * 128))[h4];
            }
            *(float4*)(&es[nn][sb][h4 * 4]) = v;
        }
        __syncthreads();
        float a0[8] = {0, 0, 0, 0, 0, 0, 0, 0};
        float a1[8] = {0, 0, 0, 0, 0, 0, 0, 0};
#pragma unroll 2
        for (int h = 0; h < 128; h += 4) {
            float p00 = pb0[(h + 0) * 192], p01 = pb0[(h + 1) * 192];
            float p02 = pb0[(h + 2) * 192], p03 = pb0[(h + 3) * 192];
            float p10 = pb1[(h + 0) * 192], p11 = pb1[(h + 1) * 192];
            float p12 = pb1[(h + 2) * 192], p13 = pb1[(h + 3) * 192];
#pragma unroll
            for (int sb = 0; sb < 8; sb++) {
                float4 e0 = *(const float4*)(&es[0][sb][h]);
                float4 e1 = *(const float4*)(&es[1][sb][h]);
                a0[sb] += e0.x * p00; a0[sb] += e0.y * p01;
                a0[sb] += e0.z * p02; a0[sb] += e0.w * p03;
                a1[sb] += e1.x * p10; a1[sb] += e1.y * p11;
                a1[sb] += e1.z * p12; a1[sb] += e1.w * p13;
            }
        }
#pragma unroll
        for (int sb = 0; sb < 8; sb++) {
            if (sb < np) {
                int bb = loc[s0 + sb];
                part[((size_t)bb * 128 + n0) * 192 + t] = a0[sb];
                part[((size_t)bb * 128 + n0 + 1) * 192 + t] = a1[sb];
            }
        }
    }
}

// ---- reduce 128 n-partials, scale by regime weight, softmax over 192 ----
__global__ void finalize_kernel(const float* __restrict__ part, const float* __restrict__ sel_w,
                                float* __restrict__ out) {
    int b = blockIdx.x, t = threadIdx.x;
    __shared__ float red[4];
    float v = 0.f;
#pragma unroll 8
    for (int c = 0; c < 128; c++) v += part[((size_t)b * 128 + c) * 192 + t];
    v *= sel_w[b];
    float mx = block_max(v, red);
    float e = expf(v - mx);
    float s = block_sum(e, red);
    out[(size_t)b * 192 + t] = e / s;
}

extern "C" void kernel_launch(void* const* d_in, const int* in_sizes, int n_in,
                              void* d_out, int out_size, void* d_ws, size_t ws_size,
                              hipStream_t stream) {
    const float* in_lt = (const float*)d_in[0];
    const float* in_st = (const float*)d_in[1];
    const float* Ws  = (const float*)d_in[2];  const float* bs  = (const float*)d_in[3];
    const float* Wt  = (const float*)d_in[4];  const float* bt  = (const float*)d_in[5];
    const float* Wh1 = (const float*)d_in[6];  const float* bh1 = (const float*)d_in[7];
    const float* Wl1 = (const float*)d_in[8];  const float* bl1 = (const float*)d_in[9];
    const float* Wh2 = (const float*)d_in[10]; const float* bh2 = (const float*)d_in[11];
    const float* Wl2 = (const float*)d_in[12]; const float* bl2 = (const float*)d_in[13];
    const float* Wh3 = (const float*)d_in[14]; const float* bh3 = (const float*)d_in[15];
    const float* Wl3 = (const float*)d_in[16]; const float* bl3 = (const float*)d_in[17];
    const float* Wr  = (const float*)d_in[18]; const float* br  = (const float*)d_in[19];
    const float* proto = (const float*)d_in[20];
    float* out = (float*)d_out;

    float* ws = (float*)d_ws;
    size_t off = 0;
    float* e_lt = ws + off; off += (size_t)32 * 512 * 128;   // [(b,l)][h]
    float* e_st = ws + off; off += (size_t)32 * 128 * 128;   // [b,n][h]
    float* O1T = ws + off; off += (size_t)128 * 16384;       // [h][(b,l)]
    float* O2T = ws + off; off += (size_t)256 * 4096;        // [l2][(b,h)]
    float* O3T = ws + off; off += (size_t)128 * 8192;        // [h][(b,l2)]
    float* O4T = ws + off; off += (size_t)128 * 4096;        // [l3][(b,h)]
    float* O5T = ws + off; off += (size_t)128 * 4096;        // [h][(b,l3)]
    float* O6 = ws + off; off += (size_t)32 * 128 * 64;      // [b][h][l4]
    float* part = ws + off; off += (size_t)32 * 128 * 192;
    float* sel_w = ws + off; off += 32;
    int* sel_r = (int*)(ws + off); off += 32;

    // encode: wave-per-(b,l), 4 l per block; lt chunks [0,128), st [128,160)
    encode_kernel<<<dim3(160, 32), 256, 0, stream>>>(in_lt, in_st, Ws, bs, Wt, bt, e_lt, e_st);
    // h1: flat 16384 rows, K=128, N=128; WR=4 (MT=32) -> O1T[h][16384]
    lbr_wave<128, 128, 4, true><<<dim3(512, 1), 256, 0, stream>>>(
        e_lt, 128, 0, Wh1, bh1, O1T, 16384, 0);
    // l1: rows=h(128)/b, K=512, N=256; WR=4 (MT=16) halves the 1 GB W-stream
    lbr_wave<512, 256, 4, true><<<dim3(8, 32), 256, 0, stream>>>(
        O1T, 16384, 512, Wl1, bl1, O2T, 4096, 128);
    // h2: rows=l2(256)/b, K=128, N=128; WR=4 (MT=32) -> O3T[h][8192]
    lbr_wave<128, 128, 4, true><<<dim3(8, 32), 256, 0, stream>>>(
        O2T, 4096, 128, Wh2, bh2, O3T, 8192, 256);
    // l2: rows=h(128)/b, K=256, N=128; WR=2 (MT=16) -> O4T[l3][4096]
    lbr_wave<256, 128, 2, true><<<dim3(8, 32), 256, 0, stream>>>(
        O3T, 8192, 256, Wl2, bl2, O4T, 4096, 128);
    // h3: rows=l3(128)/b, K=128, N=128; WR=2 (MT=16) -> O5T[h][4096]
    lbr_wave<128, 128, 2, true><<<dim3(8, 32), 256, 0, stream>>>(
        O4T, 4096, 128, Wh3, bh3, O5T, 4096, 128);
    // l3: rows=h(128)/b, K=128, N=64; WR=1 (MT=16); natural out [b][h][l4]
    lbr_wave<128, 64, 1, false><<<dim3(8, 32), 256, 0, stream>>>(
        O5T, 4096, 128, Wl3, bl3, O6, 0, 8192);
    logits_select<<<32, 256, 0, stream>>>(O6, Wr, br, sel_w, sel_r);
    einsum_nsplit<<<dim3(64, 8), 192, 0, stream>>>(e_st, proto, sel_r, part);
    finalize_kernel<<<32, 192, 0, stream>>>(part, sel_w, out);
}

// Round 2
// 371.656 us; speedup vs baseline: 1.0148x; 1.0148x over previous
//
#include <hip/hip_runtime.h>
#include <math.h>

#define EPS 1e-5f

__device__ __forceinline__ float gelu_exact(float x) {
    return 0.5f * x * (1.0f + erff(x * 0.7071067811865476f));
}

// ---- block reductions for finalize (192 threads = 3 waves) ----
__device__ float block_sum(float v, float* red) {
    int lane = threadIdx.x & 63, wid = threadIdx.x >> 6;
#pragma unroll
    for (int off = 32; off > 0; off >>= 1) v += __shfl_down(v, off, 64);
    if (lane == 0) red[wid] = v;
    __syncthreads();
    int nw = ((int)blockDim.x + 63) >> 6;
    float s = red[0];
    for (int w = 1; w < nw; w++) s += red[w];
    __syncthreads();
    return s;
}

__device__ float block_max(float v, float* red) {
    int lane = threadIdx.x & 63, wid = threadIdx.x >> 6;
#pragma unroll
    for (int off = 32; off > 0; off >>= 1) v = fmaxf(v, __shfl_down(v, off, 64));
    if (lane == 0) red[wid] = v;
    __syncthreads();
    int nw = ((int)blockDim.x + 63) >> 6;
    float s = red[0];
    for (int w = 1; w < nw; w++) s = fmaxf(s, red[w]);
    __syncthreads();
    return s;
}

// ---- threefry2x32-20 (JAX PRNG), partitionable scheme (verified round 1) ----
__device__ void threefry2x32(unsigned k0, unsigned k1, unsigned x0, unsigned x1,
                             unsigned& o0, unsigned& o1) {
    unsigned ks[3] = {k0, k1, k0 ^ k1 ^ 0x1BD11BDAu};
    const unsigned rot[2][4] = {{13u, 15u, 26u, 6u}, {17u, 29u, 16u, 24u}};
    x0 += ks[0]; x1 += ks[1];
#pragma unroll
    for (int i = 0; i < 5; i++) {
#pragma unroll
        for (int j = 0; j < 4; j++) {
            unsigned r = rot[i & 1][j];
            x0 += x1;
            x1 = (x1 << r) | (x1 >> (32 - r));
            x1 ^= x0;
        }
        x0 += ks[(i + 1) % 3];
        x1 += ks[(i + 2) % 3] + (unsigned)(i + 1);
    }
    o0 = x0; o1 = x1;
}

__device__ float gumbel_at(int j) {
    unsigned o0, o1;
    threefry2x32(0u, 42u, 0u, (unsigned)j, o0, o1);
    unsigned bits = o0 ^ o1;
    float f = __uint_as_float((bits >> 9) | 0x3F800000u) - 1.0f;  // [0,1)
    float u = fmaxf(f + 1.17549435e-38f, 1.17549435e-38f);
    return -logf(-logf(u));
}

// ---- encode, wave-per-(b,l): 4 waves/block each own one l; wave-private
// LDS window (25 rows x 9 ch); H=128 InstanceNorm via in-wave shfl_xor
// butterflies (2 h per lane). Only 2 barriers, no cross-wave reductions. ----
__global__ __launch_bounds__(256) void encode_kernel(
    const float* __restrict__ x_lt, const float* __restrict__ x_st,
    const float* __restrict__ Ws, const float* __restrict__ bs,
    const float* __restrict__ Wt, const float* __restrict__ bt,
    float* __restrict__ e_lt, float* __restrict__ e_st) {
    const int b = blockIdx.y;
    const int w = threadIdx.x >> 6, ln = threadIdx.x & 63;
    const float* x; float* e; int L, l;
    if (blockIdx.x < 128) { x = x_lt; e = e_lt; L = 512; l = blockIdx.x * 4 + w; }
    else { x = x_st; e = e_st; L = 128; l = (blockIdx.x - 128) * 4 + w; }
    __shared__ float xw_all[4][228];   // 225 window values per wave
    __shared__ float sm_all[4][20];    // seas[0..8], mm[10..18] per wave
    float* xw = xw_all[w];
    float* sm = sm_all[w];
    const float* xb = x + (size_t)b * L * 9;
#pragma unroll
    for (int q = 0; q < 4; q++) {
        int f = ln + 64 * q;
        if (f < 225) {
            int row = f / 9, c = f - row * 9;
            int rr = l - 12 + row;
            rr = rr < 0 ? 0 : (rr >= L ? L - 1 : rr);
            xw[f] = xb[(size_t)rr * 9 + c];
        }
    }
    __syncthreads();
    if (ln < 9) {
        float s = 0.f;
#pragma unroll
        for (int j = 0; j < 25; j++) s += xw[j * 9 + ln];
        float x0 = xb[ln];                       // x[b][0][c]
        float mm = (s - 25.f * x0) * (1.0f / 25.0f);
        sm[ln] = (xw[108 + ln] - x0) - mm;       // seas: x[l]-x0 - (mm-x0)
        sm[ln + 10] = mm;                        // trend input
    }
    __syncthreads();
    // each lane owns h = ln and h = ln+64
    float ysA = bs[ln], ysB = bs[ln + 64];
    float ytA = bt[ln], ytB = bt[ln + 64];
#pragma unroll
    for (int c = 0; c < 9; c++) {
        float sv = sm[c], mv = sm[c + 10];
        ysA += sv * Ws[c * 128 + ln];
        ysB += sv * Ws[c * 128 + ln + 64];
        ytA += mv * Wt[c * 128 + ln];
        ytB += mv * Wt[c * 128 + ln + 64];
    }
    float sa = ysA + ysB, sb2 = ytA + ytB;
#pragma unroll
    for (int off = 32; off > 0; off >>= 1) {
        sa += __shfl_xor(sa, off, 64);
        sb2 += __shfl_xor(sb2, off, 64);
    }
    float ms = sa * (1.0f / 128.0f), mt = sb2 * (1.0f / 128.0f);
    float dA = ysA - ms, dB = ysB - ms;
    float tA = ytA - mt, tB = ytB - mt;
    float qa = dA * dA + dB * dB, qb = tA * tA + tB * tB;
#pragma unroll
    for (int off = 32; off > 0; off >>= 1) {
        qa += __shfl_xor(qa, off, 64);
        qb += __shfl_xor(qb, off, 64);
    }
    float inva = rsqrtf(qa * (1.0f / 128.0f) + EPS);
    float invb = rsqrtf(qb * (1.0f / 128.0f) + EPS);
    float* eo = e + ((size_t)b * L + l) * 128;
    eo[ln] = gelu_exact(dA * inva) + gelu_exact(tA * invb);
    eo[ln + 64] = gelu_exact(dB * inva) + gelu_exact(tB * invb);
}

// ---- wave-autonomous Linear -> InstanceNorm -> GELU, transposed-output.
// K-loop steps by 4: WR float4 A-reads (broadcast) from wave-private LDS +
// 4 float4 W loads, 16*WR FMAs per step.
// Occupancy rule (round-1 lesson): keep grid >= 512 blocks (2 blk/CU); WR
// bumps that drop to 1 blk/CU regress (latency-bound, not L1-BW-bound).
template <int K, int N, int WR, bool TRANS>
__global__ __launch_bounds__(256) void lbr_wave(
    const float* __restrict__ A, int S, int ABOFF,
    const float* __restrict__ W, const float* __restrict__ bias,
    float* __restrict__ out, int OROWS, int OBOFF) {
    constexpr int CG = N / 4;        // lanes covering the N dimension
    constexpr int SG = 64 / CG;      // row-subgroups per wave
    constexpr int RW = SG * WR;      // rows per wave
    constexpr int MT = 4 * RW;       // rows per block
    constexpr int LOG2MT = (MT == 8) ? 3 : ((MT == 16) ? 4 : 5);
    constexpr int STAGE = 4 * RW * K;
    constexpr int TILE = TRANS ? MT * (N + 4) : 0;
    constexpr int LSZ = STAGE > TILE ? STAGE : TILE;
    __shared__ __align__(16) float lds[LSZ];
    const int t = threadIdx.x;
    const int w = t >> 6, ln = t & 63;
    const int sg = ln / CG;
    const int n0 = (ln % CG) * 4;
    const int b = blockIdx.y;
    const int r0b = blockIdx.x * MT;
    const int r0w = r0b + w * RW;
    float* As = lds + w * RW * K;
    const float* Ab = A + (size_t)b * ABOFF;
    for (int idx = ln; idx < RW * (K / 4); idx += 64) {
        int rr = idx / (K / 4), kk = idx % (K / 4);
        float4 v = *(const float4*)(Ab + (size_t)(r0w + rr) * S + kk * 4);
        *(float4*)(As + rr * K + kk * 4) = v;
    }
    float4 acc[WR];
    {
        float4 bv = *(const float4*)(bias + n0);
#pragma unroll
        for (int j = 0; j < WR; j++) acc[j] = bv;
    }
    const float* ap = As + (sg * WR) * K;
    const float* wp = W + n0;
#pragma unroll 2
    for (int k = 0; k < K; k += 4) {
        float4 w0 = *(const float4*)(wp);
        float4 w1 = *(const float4*)(wp + N);
        float4 w2 = *(const float4*)(wp + 2 * N);
        float4 w3 = *(const float4*)(wp + 3 * N);
        wp += 4 * N;
#pragma unroll
        for (int j = 0; j < WR; j++) {
            float4 a4 = *(const float4*)(ap + j * K + k);
            acc[j].x += a4.x * w0.x; acc[j].y += a4.x * w0.y;
            acc[j].z += a4.x * w0.z; acc[j].w += a4.x * w0.w;
            acc[j].x += a4.y * w1.x; acc[j].y += a4.y * w1.y;
            acc[j].z += a4.y * w1.z; acc[j].w += a4.y * w1.w;
            acc[j].x += a4.z * w2.x; acc[j].y += a4.z * w2.y;
            acc[j].z += a4.z * w2.z; acc[j].w += a4.z * w2.w;
            acc[j].x += a4.w * w3.x; acc[j].y += a4.w * w3.y;
            acc[j].z += a4.w * w3.z; acc[j].w += a4.w * w3.w;
        }
    }
    float4 res[WR];
#pragma unroll
    for (int j = 0; j < WR; j++) {
        float s = acc[j].x + acc[j].y + acc[j].z + acc[j].w;
#pragma unroll
        for (int off = CG / 2; off > 0; off >>= 1) s += __shfl_xor(s, off, 64);
        float m = s * (1.0f / (float)N);
        float dx = acc[j].x - m, dy = acc[j].y - m, dz = acc[j].z - m, dw = acc[j].w - m;
        float q = dx * dx + dy * dy + dz * dz + dw * dw;
#pragma unroll
        for (int off = CG / 2; off > 0; off >>= 1) q += __shfl_xor(q, off, 64);
        float inv = rsqrtf(q * (1.0f / (float)N) + EPS);
        res[j].x = gelu_exact(dx * inv);
        res[j].y = gelu_exact(dy * inv);
        res[j].z = gelu_exact(dz * inv);
        res[j].w = gelu_exact(dw * inv);
    }
    if constexpr (TRANS) {
        __syncthreads();
#pragma unroll
        for (int j = 0; j < WR; j++) {
            int rl = w * RW + sg * WR + j;
            *(float4*)(lds + rl * (N + 4) + n0) = res[j];
        }
        __syncthreads();
        float* ob = out + (size_t)b * OBOFF + r0b;
        for (int e = t; e < MT * N; e += 256) {
            int r = e & (MT - 1), n = e >> LOG2MT;
            ob[(size_t)n * OROWS + r] = lds[r * (N + 4) + n];
        }
    } else {
        float* ob = out + (size_t)b * OBOFF;
#pragma unroll
        for (int j = 0; j < WR; j++) {
            int row = r0w + sg * WR + j;
            *(float4*)(ob + (size_t)row * N + n0) = res[j];
        }
    }
}

// ---- fused logits + gumbel-softmax(hard) selection. grid 32 (b), block 256. ----
__global__ __launch_bounds__(256) void logits_select(
    const float* __restrict__ O6, const float* __restrict__ Wr,
    const float* __restrict__ br, float* __restrict__ sel_w, int* __restrict__ sel_r) {
    int b = blockIdx.x, t = threadIdx.x;
    __shared__ float sO6[128 * 68];
    __shared__ float red[4][8];
    const float4* ob4 = (const float4*)(O6 + (size_t)b * 8192);
    for (int i4 = t; i4 < 2048; i4 += 256) {
        float4 v = ob4[i4];
        int p = i4 * 4;
        int h = p >> 6, l4 = p & 63;
        *(float4*)(&sO6[h * 68 + l4]) = v;
    }
    __syncthreads();
    float acc[8] = {0, 0, 0, 0, 0, 0, 0, 0};
#pragma unroll 4
    for (int q = 0; q < 32; q++) {
        int i = q * 256 + t;  // logits flat index: l4 = i>>7, h = i&127
        int l4 = i >> 7, h = i & 127;
        float v = sO6[h * 68 + l4];
        const float4* wr = (const float4*)(Wr + (size_t)i * 8);
        float4 w0 = wr[0], w1 = wr[1];
        acc[0] += v * w0.x; acc[1] += v * w0.y; acc[2] += v * w0.z; acc[3] += v * w0.w;
        acc[4] += v * w1.x; acc[5] += v * w1.y; acc[6] += v * w1.z; acc[7] += v * w1.w;
    }
#pragma unroll
    for (int j = 0; j < 8; j++)
#pragma unroll
        for (int off = 32; off > 0; off >>= 1) acc[j] += __shfl_xor(acc[j], off, 64);
    int lane = t & 63, wid = t >> 6;
    if (lane == 0)
        for (int j = 0; j < 8; j++) red[wid][j] = acc[j];
    __syncthreads();
    if (t == 0) {
        float z[8];
        for (int j = 0; j < 8; j++) {
            float lg = br[j] + red[0][j] + red[1][j] + red[2][j] + red[3][j];
            z[j] = lg + gumbel_at(b * 8 + j);
        }
        int am = 0;
        float zm = z[0];
        for (int j = 1; j < 8; j++)
            if (z[j] > zm) { zm = z[j]; am = j; }
        float ssum = 0.f;
        for (int j = 0; j < 8; j++) ssum += expf(z[j] - zm);
        float s = 1.0f / ssum;
        sel_w[b] = (1.0f - s) + s;
        sel_r[b] = am;
    }
}

// ---- regime-grouped einsum, h-split for occupancy. grid (128 n, 8 r, 2 hz),
// block 192 (t = m*3+o) -> 2048 blocks, ~24 waves/CU. Proto read 8 h-rows
// deep (8 outstanding 256B/wave scalar loads); es staged in LDS, read as
// float4. part is [hz][b][n][t]; finalize sums both halves. ----
__global__ __launch_bounds__(192) void einsum_nsplit(
    const float* __restrict__ e_st, const float* __restrict__ proto,
    const int* __restrict__ sel_r, float* __restrict__ part) {
    const int n = blockIdx.x, r = blockIdx.y, hz = blockIdx.z, t = threadIdx.x;
    __shared__ int loc[32];
    __shared__ int s_gs;
    if (t == 0) {
        int g = 0;
        for (int bb = 0; bb < 32; bb++)
            if (sel_r[bb] == r) loc[g++] = bb;
        s_gs = g;
    }
    __syncthreads();
    const int gs = s_gs;
    if (gs == 0) return;
    __shared__ __align__(16) float es[8][64];
    const float* pb = proto + (((size_t)r * 128 + n) * 128 + hz * 64) * 192 + t;
    float* po = part + (size_t)hz * (32 * 128 * 192);
    for (int s0 = 0; s0 < gs; s0 += 8) {
        int np = gs - s0 < 8 ? gs - s0 : 8;
        __syncthreads();
        for (int i = t; i < 512; i += 192) {
            int sb = i >> 6, h = i & 63;
            float v = 0.f;
            if (sb < np)
                v = e_st[((size_t)loc[s0 + sb] * 128 + n) * 128 + hz * 64 + h];
            es[sb][h] = v;
        }
        __syncthreads();
        float a[8] = {0, 0, 0, 0, 0, 0, 0, 0};
#pragma unroll
        for (int h = 0; h < 64; h += 8) {
            float p[8];
#pragma unroll
            for (int u = 0; u < 8; u++) p[u] = pb[(size_t)(h + u) * 192];
#pragma unroll
            for (int sb = 0; sb < 8; sb++) {
                float4 e0 = *(const float4*)(&es[sb][h]);
                float4 e1 = *(const float4*)(&es[sb][h + 4]);
                a[sb] += e0.x * p[0] + e0.y * p[1] + e0.z * p[2] + e0.w * p[3]
                       + e1.x * p[4] + e1.y * p[5] + e1.z * p[6] + e1.w * p[7];
            }
        }
#pragma unroll
        for (int sb = 0; sb < 8; sb++) {
            if (sb < np) {
                int bb = loc[s0 + sb];
                po[((size_t)bb * 128 + n) * 192 + t] = a[sb];
            }
        }
    }
}

// ---- reduce 2x128 n-partials, scale by regime weight, softmax over 192 ----
__global__ void finalize_kernel(const float* __restrict__ part, const float* __restrict__ sel_w,
                                float* __restrict__ out) {
    int b = blockIdx.x, t = threadIdx.x;
    __shared__ float red[4];
    const float* p0 = part + (size_t)b * 128 * 192 + t;
    const float* p1 = p0 + (size_t)32 * 128 * 192;
    float v = 0.f;
#pragma unroll 8
    for (int c = 0; c < 128; c++) {
        v += p0[(size_t)c * 192];
        v += p1[(size_t)c * 192];
    }
    v *= sel_w[b];
    float mx = block_max(v, red);
    float e = expf(v - mx);
    float s = block_sum(e, red);
    out[(size_t)b * 192 + t] = e / s;
}

extern "C" void kernel_launch(void* const* d_in, const int* in_sizes, int n_in,
                              void* d_out, int out_size, void* d_ws, size_t ws_size,
                              hipStream_t stream) {
    const float* in_lt = (const float*)d_in[0];
    const float* in_st = (const float*)d_in[1];
    const float* Ws  = (const float*)d_in[2];  const float* bs  = (const float*)d_in[3];
    const float* Wt  = (const float*)d_in[4];  const float* bt  = (const float*)d_in[5];
    const float* Wh1 = (const float*)d_in[6];  const float* bh1 = (const float*)d_in[7];
    const float* Wl1 = (const float*)d_in[8];  const float* bl1 = (const float*)d_in[9];
    const float* Wh2 = (const float*)d_in[10]; const float* bh2 = (const float*)d_in[11];
    const float* Wl2 = (const float*)d_in[12]; const float* bl2 = (const float*)d_in[13];
    const float* Wh3 = (const float*)d_in[14]; const float* bh3 = (const float*)d_in[15];
    const float* Wl3 = (const float*)d_in[16]; const float* bl3 = (const float*)d_in[17];
    const float* Wr  = (const float*)d_in[18]; const float* br  = (const float*)d_in[19];
    const float* proto = (const float*)d_in[20];
    float* out = (float*)d_out;

    float* ws = (float*)d_ws;
    size_t off = 0;
    float* e_lt = ws + off; off += (size_t)32 * 512 * 128;   // [(b,l)][h]
    float* e_st = ws + off; off += (size_t)32 * 128 * 128;   // [b,n][h]
    float* O1T = ws + off; off += (size_t)128 * 16384;       // [h][(b,l)]
    float* O2T = ws + off; off += (size_t)256 * 4096;        // [l2][(b,h)]
    float* O3T = ws + off; off += (size_t)128 * 8192;        // [h][(b,l2)]
    float* O4T = ws + off; off += (size_t)128 * 4096;        // [l3][(b,h)]
    float* O5T = ws + off; off += (size_t)128 * 4096;        // [h][(b,l3)]
    float* O6 = ws + off; off += (size_t)32 * 128 * 64;      // [b][h][l4]
    float* part = ws + off; off += (size_t)2 * 32 * 128 * 192;  // [hz][b][n][t]
    float* sel_w = ws + off; off += 32;
    int* sel_r = (int*)(ws + off); off += 32;

    // encode: wave-per-(b,l), 4 l per block; lt chunks [0,128), st [128,160)
    encode_kernel<<<dim3(160, 32), 256, 0, stream>>>(in_lt, in_st, Ws, bs, Wt, bt, e_lt, e_st);
    // h1: flat 16384 rows, K=128, N=128; WR=4 (MT=32), grid 512 (2 blk/CU)
    lbr_wave<128, 128, 4, true><<<dim3(512, 1), 256, 0, stream>>>(
        e_lt, 128, 0, Wh1, bh1, O1T, 16384, 0);
    // l1: rows=h(128)/b, K=512, N=256; WR=2 (MT=8), grid 512
    lbr_wave<512, 256, 2, true><<<dim3(16, 32), 256, 0, stream>>>(
        O1T, 16384, 512, Wl1, bl1, O2T, 4096, 128);
    // h2: rows=l2(256)/b, K=128, N=128; WR=2 (MT=16), grid 512
    lbr_wave<128, 128, 2, true><<<dim3(16, 32), 256, 0, stream>>>(
        O2T, 4096, 128, Wh2, bh2, O3T, 8192, 256);
    // l2: rows=h(128)/b, K=256, N=128; WR=1 (MT=8), grid 512
    lbr_wave<256, 128, 1, true><<<dim3(16, 32), 256, 0, stream>>>(
        O3T, 8192, 256, Wl2, bl2, O4T, 4096, 128);
    // h3: rows=l3(128)/b, K=128, N=128; WR=1 (MT=8), grid 512
    lbr_wave<128, 128, 1, true><<<dim3(16, 32), 256, 0, stream>>>(
        O4T, 4096, 128, Wh3, bh3, O5T, 4096, 128);
    // l3: rows=h(128)/b, K=128, N=64; WR=1 (MT=16); natural out [b][h][l4]
    lbr_wave<128, 64, 1, false><<<dim3(8, 32), 256, 0, stream>>>(
        O5T, 4096, 128, Wl3, bl3, O6, 0, 8192);
    logits_select<<<32, 256, 0, stream>>>(O6, Wr, br, sel_w, sel_r);
    einsum_nsplit<<<dim3(128, 8, 2), 192, 0, stream>>>(e_st, proto, sel_r, part);
    finalize_kernel<<<32, 192, 0, stream>>>(part, sel_w, out);
}

// Round 3
// 359.082 us; speedup vs baseline: 1.0503x; 1.0350x over previous
//
#include <hip/hip_runtime.h>
#include <math.h>

#define EPS 1e-5f

__device__ __forceinline__ float gelu_exact(float x) {
    return 0.5f * x * (1.0f + erff(x * 0.7071067811865476f));
}

// ---- block reductions for finalize (192 threads = 3 waves) ----
__device__ float block_sum(float v, float* red) {
    int lane = threadIdx.x & 63, wid = threadIdx.x >> 6;
#pragma unroll
    for (int off = 32; off > 0; off >>= 1) v += __shfl_down(v, off, 64);
    if (lane == 0) red[wid] = v;
    __syncthreads();
    int nw = ((int)blockDim.x + 63) >> 6;
    float s = red[0];
    for (int w = 1; w < nw; w++) s += red[w];
    __syncthreads();
    return s;
}

__device__ float block_max(float v, float* red) {
    int lane = threadIdx.x & 63, wid = threadIdx.x >> 6;
#pragma unroll
    for (int off = 32; off > 0; off >>= 1) v = fmaxf(v, __shfl_down(v, off, 64));
    if (lane == 0) red[wid] = v;
    __syncthreads();
    int nw = ((int)blockDim.x + 63) >> 6;
    float s = red[0];
    for (int w = 1; w < nw; w++) s = fmaxf(s, red[w]);
    __syncthreads();
    return s;
}

// ---- threefry2x32-20 (JAX PRNG), partitionable scheme (verified round 1) ----
__device__ void threefry2x32(unsigned k0, unsigned k1, unsigned x0, unsigned x1,
                             unsigned& o0, unsigned& o1) {
    unsigned ks[3] = {k0, k1, k0 ^ k1 ^ 0x1BD11BDAu};
    const unsigned rot[2][4] = {{13u, 15u, 26u, 6u}, {17u, 29u, 16u, 24u}};
    x0 += ks[0]; x1 += ks[1];
#pragma unroll
    for (int i = 0; i < 5; i++) {
#pragma unroll
        for (int j = 0; j < 4; j++) {
            unsigned r = rot[i & 1][j];
            x0 += x1;
            x1 = (x1 << r) | (x1 >> (32 - r));
            x1 ^= x0;
        }
        x0 += ks[(i + 1) % 3];
        x1 += ks[(i + 2) % 3] + (unsigned)(i + 1);
    }
    o0 = x0; o1 = x1;
}

__device__ float gumbel_at(int j) {
    unsigned o0, o1;
    threefry2x32(0u, 42u, 0u, (unsigned)j, o0, o1);
    unsigned bits = o0 ^ o1;
    float f = __uint_as_float((bits >> 9) | 0x3F800000u) - 1.0f;  // [0,1)
    float u = fmaxf(f + 1.17549435e-38f, 1.17549435e-38f);
    return -logf(-logf(u));
}

// ---- encode, wave-per-(b,l): 4 waves/block each own one l; wave-private
// LDS window (25 rows x 9 ch); H=128 InstanceNorm via in-wave shfl_xor
// butterflies (2 h per lane). Only 2 barriers, no cross-wave reductions. ----
__global__ __launch_bounds__(256) void encode_kernel(
    const float* __restrict__ x_lt, const float* __restrict__ x_st,
    const float* __restrict__ Ws, const float* __restrict__ bs,
    const float* __restrict__ Wt, const float* __restrict__ bt,
    float* __restrict__ e_lt, float* __restrict__ e_st) {
    const int b = blockIdx.y;
    const int w = threadIdx.x >> 6, ln = threadIdx.x & 63;
    const float* x; float* e; int L, l;
    if (blockIdx.x < 128) { x = x_lt; e = e_lt; L = 512; l = blockIdx.x * 4 + w; }
    else { x = x_st; e = e_st; L = 128; l = (blockIdx.x - 128) * 4 + w; }
    __shared__ float xw_all[4][228];   // 225 window values per wave
    __shared__ float sm_all[4][20];    // seas[0..8], mm[10..18] per wave
    float* xw = xw_all[w];
    float* sm = sm_all[w];
    const float* xb = x + (size_t)b * L * 9;
#pragma unroll
    for (int q = 0; q < 4; q++) {
        int f = ln + 64 * q;
        if (f < 225) {
            int row = f / 9, c = f - row * 9;
            int rr = l - 12 + row;
            rr = rr < 0 ? 0 : (rr >= L ? L - 1 : rr);
            xw[f] = xb[(size_t)rr * 9 + c];
        }
    }
    __syncthreads();
    if (ln < 9) {
        float s = 0.f;
#pragma unroll
        for (int j = 0; j < 25; j++) s += xw[j * 9 + ln];
        float x0 = xb[ln];                       // x[b][0][c]
        float mm = (s - 25.f * x0) * (1.0f / 25.0f);
        sm[ln] = (xw[108 + ln] - x0) - mm;       // seas: x[l]-x0 - (mm-x0)
        sm[ln + 10] = mm;                        // trend input
    }
    __syncthreads();
    // each lane owns h = ln and h = ln+64
    float ysA = bs[ln], ysB = bs[ln + 64];
    float ytA = bt[ln], ytB = bt[ln + 64];
#pragma unroll
    for (int c = 0; c < 9; c++) {
        float sv = sm[c], mv = sm[c + 10];
        ysA += sv * Ws[c * 128 + ln];
        ysB += sv * Ws[c * 128 + ln + 64];
        ytA += mv * Wt[c * 128 + ln];
        ytB += mv * Wt[c * 128 + ln + 64];
    }
    float sa = ysA + ysB, sb2 = ytA + ytB;
#pragma unroll
    for (int off = 32; off > 0; off >>= 1) {
        sa += __shfl_xor(sa, off, 64);
        sb2 += __shfl_xor(sb2, off, 64);
    }
    float ms = sa * (1.0f / 128.0f), mt = sb2 * (1.0f / 128.0f);
    float dA = ysA - ms, dB = ysB - ms;
    float tA = ytA - mt, tB = ytB - mt;
    float qa = dA * dA + dB * dB, qb = tA * tA + tB * tB;
#pragma unroll
    for (int off = 32; off > 0; off >>= 1) {
        qa += __shfl_xor(qa, off, 64);
        qb += __shfl_xor(qb, off, 64);
    }
    float inva = rsqrtf(qa * (1.0f / 128.0f) + EPS);
    float invb = rsqrtf(qb * (1.0f / 128.0f) + EPS);
    float* eo = e + ((size_t)b * L + l) * 128;
    eo[ln] = gelu_exact(dA * inva) + gelu_exact(tA * invb);
    eo[ln + 64] = gelu_exact(dB * inva) + gelu_exact(tB * invb);
}

// ---- wave-autonomous Linear -> InstanceNorm -> GELU, transposed-output.
// K-loop steps by 4: WR float4 A-reads (broadcast) from wave-private LDS +
// 4 float4 W loads, 16*WR FMAs per step.
// Occupancy rule (round-1 lesson): keep grid >= 512 blocks (2 blk/CU); WR
// bumps that drop to 1 blk/CU regress (latency-bound, not L1-BW-bound).
template <int K, int N, int WR, bool TRANS>
__global__ __launch_bounds__(256) void lbr_wave(
    const float* __restrict__ A, int S, int ABOFF,
    const float* __restrict__ W, const float* __restrict__ bias,
    float* __restrict__ out, int OROWS, int OBOFF) {
    constexpr int CG = N / 4;        // lanes covering the N dimension
    constexpr int SG = 64 / CG;      // row-subgroups per wave
    constexpr int RW = SG * WR;      // rows per wave
    constexpr int MT = 4 * RW;       // rows per block
    constexpr int LOG2MT = (MT == 8) ? 3 : ((MT == 16) ? 4 : 5);
    constexpr int STAGE = 4 * RW * K;
    constexpr int TILE = TRANS ? MT * (N + 4) : 0;
    constexpr int LSZ = STAGE > TILE ? STAGE : TILE;
    __shared__ __align__(16) float lds[LSZ];
    const int t = threadIdx.x;
    const int w = t >> 6, ln = t & 63;
    const int sg = ln / CG;
    const int n0 = (ln % CG) * 4;
    const int b = blockIdx.y;
    const int r0b = blockIdx.x * MT;
    const int r0w = r0b + w * RW;
    float* As = lds + w * RW * K;
    const float* Ab = A + (size_t)b * ABOFF;
    for (int idx = ln; idx < RW * (K / 4); idx += 64) {
        int rr = idx / (K / 4), kk = idx % (K / 4);
        float4 v = *(const float4*)(Ab + (size_t)(r0w + rr) * S + kk * 4);
        *(float4*)(As + rr * K + kk * 4) = v;
    }
    float4 acc[WR];
    {
        float4 bv = *(const float4*)(bias + n0);
#pragma unroll
        for (int j = 0; j < WR; j++) acc[j] = bv;
    }
    const float* ap = As + (sg * WR) * K;
    const float* wp = W + n0;
#pragma unroll 2
    for (int k = 0; k < K; k += 4) {
        float4 w0 = *(const float4*)(wp);
        float4 w1 = *(const float4*)(wp + N);
        float4 w2 = *(const float4*)(wp + 2 * N);
        float4 w3 = *(const float4*)(wp + 3 * N);
        wp += 4 * N;
#pragma unroll
        for (int j = 0; j < WR; j++) {
            float4 a4 = *(const float4*)(ap + j * K + k);
            acc[j].x += a4.x * w0.x; acc[j].y += a4.x * w0.y;
            acc[j].z += a4.x * w0.z; acc[j].w += a4.x * w0.w;
            acc[j].x += a4.y * w1.x; acc[j].y += a4.y * w1.y;
            acc[j].z += a4.y * w1.z; acc[j].w += a4.y * w1.w;
            acc[j].x += a4.z * w2.x; acc[j].y += a4.z * w2.y;
            acc[j].z += a4.z * w2.z; acc[j].w += a4.z * w2.w;
            acc[j].x += a4.w * w3.x; acc[j].y += a4.w * w3.y;
            acc[j].z += a4.w * w3.z; acc[j].w += a4.w * w3.w;
        }
    }
    float4 res[WR];
#pragma unroll
    for (int j = 0; j < WR; j++) {
        float s = acc[j].x + acc[j].y + acc[j].z + acc[j].w;
#pragma unroll
        for (int off = CG / 2; off > 0; off >>= 1) s += __shfl_xor(s, off, 64);
        float m = s * (1.0f / (float)N);
        float dx = acc[j].x - m, dy = acc[j].y - m, dz = acc[j].z - m, dw = acc[j].w - m;
        float q = dx * dx + dy * dy + dz * dz + dw * dw;
#pragma unroll
        for (int off = CG / 2; off > 0; off >>= 1) q += __shfl_xor(q, off, 64);
        float inv = rsqrtf(q * (1.0f / (float)N) + EPS);
        res[j].x = gelu_exact(dx * inv);
        res[j].y = gelu_exact(dy * inv);
        res[j].z = gelu_exact(dz * inv);
        res[j].w = gelu_exact(dw * inv);
    }
    if constexpr (TRANS) {
        __syncthreads();
#pragma unroll
        for (int j = 0; j < WR; j++) {
            int rl = w * RW + sg * WR + j;
            *(float4*)(lds + rl * (N + 4) + n0) = res[j];
        }
        __syncthreads();
        float* ob = out + (size_t)b * OBOFF + r0b;
        for (int e = t; e < MT * N; e += 256) {
            int r = e & (MT - 1), n = e >> LOG2MT;
            ob[(size_t)n * OROWS + r] = lds[r * (N + 4) + n];
        }
    } else {
        float* ob = out + (size_t)b * OBOFF;
#pragma unroll
        for (int j = 0; j < WR; j++) {
            int row = r0w + sg * WR + j;
            *(float4*)(ob + (size_t)row * N + n0) = res[j];
        }
    }
}

// ---- fused logits + gumbel-softmax(hard) selection. grid 32 (b), block 256. ----
__global__ __launch_bounds__(256) void logits_select(
    const float* __restrict__ O6, const float* __restrict__ Wr,
    const float* __restrict__ br, float* __restrict__ sel_w, int* __restrict__ sel_r) {
    int b = blockIdx.x, t = threadIdx.x;
    __shared__ float sO6[128 * 68];
    __shared__ float red[4][8];
    const float4* ob4 = (const float4*)(O6 + (size_t)b * 8192);
    for (int i4 = t; i4 < 2048; i4 += 256) {
        float4 v = ob4[i4];
        int p = i4 * 4;
        int h = p >> 6, l4 = p & 63;
        *(float4*)(&sO6[h * 68 + l4]) = v;
    }
    __syncthreads();
    float acc[8] = {0, 0, 0, 0, 0, 0, 0, 0};
#pragma unroll 4
    for (int q = 0; q < 32; q++) {
        int i = q * 256 + t;  // logits flat index: l4 = i>>7, h = i&127
        int l4 = i >> 7, h = i & 127;
        float v = sO6[h * 68 + l4];
        const float4* wr = (const float4*)(Wr + (size_t)i * 8);
        float4 w0 = wr[0], w1 = wr[1];
        acc[0] += v * w0.x; acc[1] += v * w0.y; acc[2] += v * w0.z; acc[3] += v * w0.w;
        acc[4] += v * w1.x; acc[5] += v * w1.y; acc[6] += v * w1.z; acc[7] += v * w1.w;
    }
#pragma unroll
    for (int j = 0; j < 8; j++)
#pragma unroll
        for (int off = 32; off > 0; off >>= 1) acc[j] += __shfl_xor(acc[j], off, 64);
    int lane = t & 63, wid = t >> 6;
    if (lane == 0)
        for (int j = 0; j < 8; j++) red[wid][j] = acc[j];
    __syncthreads();
    if (t == 0) {
        float z[8];
        for (int j = 0; j < 8; j++) {
            float lg = br[j] + red[0][j] + red[1][j] + red[2][j] + red[3][j];
            z[j] = lg + gumbel_at(b * 8 + j);
        }
        int am = 0;
        float zm = z[0];
        for (int j = 1; j < 8; j++)
            if (z[j] > zm) { zm = z[j]; am = j; }
        float ssum = 0.f;
        for (int j = 0; j < 8; j++) ssum += expf(z[j] - zm);
        float s = 1.0f / ssum;
        sel_w[b] = (1.0f - s) + s;
        sel_r[b] = am;
    }
}

// ---- regime-grouped einsum v3: float4 proto reads, low VGPR, in-wave
// rowgroup reduce. grid (128 n, 8 r, 2 hz), block 192 (3 waves).
// Lane ln of wave w: quad q = w*16+(ln&15) of the 192-dim, rowgroup
// rg = ln>>4 covers h-rows rg, rg+4, ... Per iter: 1 float4 VMEM +
// 2 ds_read_b128 (es transposed [64][12]) + 32 FMA. Partials for the 4
// rowgroups live in lanes l, l+16, l+32, l+48 -> shfl_xor(16,32) reduce,
// lanes 0-15 store float4. __launch_bounds__(192,4) caps VGPR at 128. ----
__global__ __launch_bounds__(192, 4) void einsum_nsplit(
    const float* __restrict__ e_st, const float* __restrict__ proto,
    const int* __restrict__ sel_r, float* __restrict__ part) {
    const int n = blockIdx.x, r = blockIdx.y, hz = blockIdx.z, t = threadIdx.x;
    const int w = t >> 6, ln = t & 63;
    const int rg = ln >> 4;             // rowgroup 0..3
    const int q4 = (w * 16 + (ln & 15)) * 4;  // float4 offset in 192-dim
    __shared__ int loc[32];
    __shared__ int s_gs;
    if (t == 0) {
        int g = 0;
        for (int bb = 0; bb < 32; bb++)
            if (sel_r[bb] == r) loc[g++] = bb;
        s_gs = g;
    }
    __syncthreads();
    const int gs = s_gs;
    if (gs == 0) return;
    __shared__ __align__(16) float es[64][12];  // [h_local][sb], 48B rows
    const float* pb = proto + (((size_t)r * 128 + n) * 128 + hz * 64) * 192;
    float* po = part + (size_t)hz * (32 * 128 * 192);
    for (int s0 = 0; s0 < gs; s0 += 8) {
        int np = gs - s0 < 8 ? gs - s0 : 8;
        __syncthreads();
        for (int i = t; i < 512; i += 192) {
            int sb = i >> 6, h = i & 63;
            float v = 0.f;
            if (sb < np)
                v = e_st[((size_t)loc[s0 + sb] * 128 + n) * 128 + hz * 64 + h];
            es[h][sb] = v;
        }
        __syncthreads();
        float4 a[8];
#pragma unroll
        for (int sb = 0; sb < 8; sb++) a[sb] = make_float4(0.f, 0.f, 0.f, 0.f);
#pragma unroll 4
        for (int hh = 0; hh < 16; hh++) {
            int row = hh * 4 + rg;
            float4 pv = *(const float4*)(pb + (size_t)row * 192 + q4);
            float4 e0 = *(const float4*)(&es[row][0]);
            float4 e1 = *(const float4*)(&es[row][4]);
#define ACC4(j, s) a[j].x += (s) * pv.x; a[j].y += (s) * pv.y; \
                   a[j].z += (s) * pv.z; a[j].w += (s) * pv.w;
            ACC4(0, e0.x) ACC4(1, e0.y) ACC4(2, e0.z) ACC4(3, e0.w)
            ACC4(4, e1.x) ACC4(5, e1.y) ACC4(6, e1.z) ACC4(7, e1.w)
#undef ACC4
        }
        // reduce across rowgroups (lanes ln, ln^16, ln^32 hold partials)
#pragma unroll
        for (int sb = 0; sb < 8; sb++) {
            a[sb].x += __shfl_xor(a[sb].x, 16, 64);
            a[sb].y += __shfl_xor(a[sb].y, 16, 64);
            a[sb].z += __shfl_xor(a[sb].z, 16, 64);
            a[sb].w += __shfl_xor(a[sb].w, 16, 64);
            a[sb].x += __shfl_xor(a[sb].x, 32, 64);
            a[sb].y += __shfl_xor(a[sb].y, 32, 64);
            a[sb].z += __shfl_xor(a[sb].z, 32, 64);
            a[sb].w += __shfl_xor(a[sb].w, 32, 64);
        }
        if (ln < 16) {
#pragma unroll
            for (int sb = 0; sb < 8; sb++) {
                if (sb < np) {
                    int bb = loc[s0 + sb];
                    *(float4*)(po + ((size_t)bb * 128 + n) * 192 + q4) = a[sb];
                }
            }
        }
    }
}

// ---- reduce 2x128 n-partials, scale by regime weight, softmax over 192 ----
__global__ void finalize_kernel(const float* __restrict__ part, const float* __restrict__ sel_w,
                                float* __restrict__ out) {
    int b = blockIdx.x, t = threadIdx.x;
    __shared__ float red[4];
    const float* p0 = part + (size_t)b * 128 * 192 + t;
    const float* p1 = p0 + (size_t)32 * 128 * 192;
    float v = 0.f;
#pragma unroll 8
    for (int c = 0; c < 128; c++) {
        v += p0[(size_t)c * 192];
        v += p1[(size_t)c * 192];
    }
    v *= sel_w[b];
    float mx = block_max(v, red);
    float e = expf(v - mx);
    float s = block_sum(e, red);
    out[(size_t)b * 192 + t] = e / s;
}

extern "C" void kernel_launch(void* const* d_in, const int* in_sizes, int n_in,
                              void* d_out, int out_size, void* d_ws, size_t ws_size,
                              hipStream_t stream) {
    const float* in_lt = (const float*)d_in[0];
    const float* in_st = (const float*)d_in[1];
    const float* Ws  = (const float*)d_in[2];  const float* bs  = (const float*)d_in[3];
    const float* Wt  = (const float*)d_in[4];  const float* bt  = (const float*)d_in[5];
    const float* Wh1 = (const float*)d_in[6];  const float* bh1 = (const float*)d_in[7];
    const float* Wl1 = (const float*)d_in[8];  const float* bl1 = (const float*)d_in[9];
    const float* Wh2 = (const float*)d_in[10]; const float* bh2 = (const float*)d_in[11];
    const float* Wl2 = (const float*)d_in[12]; const float* bl2 = (const float*)d_in[13];
    const float* Wh3 = (const float*)d_in[14]; const float* bh3 = (const float*)d_in[15];
    const float* Wl3 = (const float*)d_in[16]; const float* bl3 = (const float*)d_in[17];
    const float* Wr  = (const float*)d_in[18]; const float* br  = (const float*)d_in[19];
    const float* proto = (const float*)d_in[20];
    float* out = (float*)d_out;

    float* ws = (float*)d_ws;
    size_t off = 0;
    float* e_lt = ws + off; off += (size_t)32 * 512 * 128;   // [(b,l)][h]
    float* e_st = ws + off; off += (size_t)32 * 128 * 128;   // [b,n][h]
    float* O1T = ws + off; off += (size_t)128 * 16384;       // [h][(b,l)]
    float* O2T = ws + off; off += (size_t)256 * 4096;        // [l2][(b,h)]
    float* O3T = ws + off; off += (size_t)128 * 8192;        // [h][(b,l2)]
    float* O4T = ws + off; off += (size_t)128 * 4096;        // [l3][(b,h)]
    float* O5T = ws + off; off += (size_t)128 * 4096;        // [h][(b,l3)]
    float* O6 = ws + off; off += (size_t)32 * 128 * 64;      // [b][h][l4]
    float* part = ws + off; off += (size_t)2 * 32 * 128 * 192;  // [hz][b][n][t]
    float* sel_w = ws + off; off += 32;
    int* sel_r = (int*)(ws + off); off += 32;

    // encode: wave-per-(b,l), 4 l per block; lt chunks [0,128), st [128,160)
    encode_kernel<<<dim3(160, 32), 256, 0, stream>>>(in_lt, in_st, Ws, bs, Wt, bt, e_lt, e_st);
    // h1: flat 16384 rows, K=128, N=128; WR=4 (MT=32), grid 512 (2 blk/CU)
    lbr_wave<128, 128, 4, true><<<dim3(512, 1), 256, 0, stream>>>(
        e_lt, 128, 0, Wh1, bh1, O1T, 16384, 0);
    // l1: rows=h(128)/b, K=512, N=256; WR=2 (MT=8), grid 512
    lbr_wave<512, 256, 2, true><<<dim3(16, 32), 256, 0, stream>>>(
        O1T, 16384, 512, Wl1, bl1, O2T, 4096, 128);
    // h2: rows=l2(256)/b, K=128, N=128; WR=2 (MT=16), grid 512
    lbr_wave<128, 128, 2, true><<<dim3(16, 32), 256, 0, stream>>>(
        O2T, 4096, 128, Wh2, bh2, O3T, 8192, 256);
    // l2: rows=h(128)/b, K=256, N=128; WR=1 (MT=8), grid 512
    lbr_wave<256, 128, 1, true><<<dim3(16, 32), 256, 0, stream>>>(
        O3T, 8192, 256, Wl2, bl2, O4T, 4096, 128);
    // h3: rows=l3(128)/b, K=128, N=128; WR=1 (MT=8), grid 512
    lbr_wave<128, 128, 1, true><<<dim3(16, 32), 256, 0, stream>>>(
        O4T, 4096, 128, Wh3, bh3, O5T, 4096, 128);
    // l3: rows=h(128)/b, K=128, N=64; WR=1 (MT=16); natural out [b][h][l4]
    lbr_wave<128, 64, 1, false><<<dim3(8, 32), 256, 0, stream>>>(
        O5T, 4096, 128, Wl3, bl3, O6, 0, 8192);
    logits_select<<<32, 256, 0, stream>>>(O6, Wr, br, sel_w, sel_r);
    einsum_nsplit<<<dim3(128, 8, 2), 192, 0, stream>>>(e_st, proto, sel_r, part);
    finalize_kernel<<<32, 192, 0, stream>>>(part, sel_w, out);
}

// Round 4
// 321.827 us; speedup vs baseline: 1.1719x; 1.1158x over previous
//
#include <hip/hip_runtime.h>
#include <math.h>

#define EPS 1e-5f

__device__ __forceinline__ float gelu_exact(float x) {
    return 0.5f * x * (1.0f + erff(x * 0.7071067811865476f));
}

// ---- block reductions for finalize (192 threads = 3 waves) ----
__device__ float block_sum(float v, float* red) {
    int lane = threadIdx.x & 63, wid = threadIdx.x >> 6;
#pragma unroll
    for (int off = 32; off > 0; off >>= 1) v += __shfl_down(v, off, 64);
    if (lane == 0) red[wid] = v;
    __syncthreads();
    int nw = ((int)blockDim.x + 63) >> 6;
    float s = red[0];
    for (int w = 1; w < nw; w++) s += red[w];
    __syncthreads();
    return s;
}

__device__ float block_max(float v, float* red) {
    int lane = threadIdx.x & 63, wid = threadIdx.x >> 6;
#pragma unroll
    for (int off = 32; off > 0; off >>= 1) v = fmaxf(v, __shfl_down(v, off, 64));
    if (lane == 0) red[wid] = v;
    __syncthreads();
    int nw = ((int)blockDim.x + 63) >> 6;
    float s = red[0];
    for (int w = 1; w < nw; w++) s = fmaxf(s, red[w]);
    __syncthreads();
    return s;
}

// ---- threefry2x32-20 (JAX PRNG), partitionable scheme (verified round 1) ----
__device__ void threefry2x32(unsigned k0, unsigned k1, unsigned x0, unsigned x1,
                             unsigned& o0, unsigned& o1) {
    unsigned ks[3] = {k0, k1, k0 ^ k1 ^ 0x1BD11BDAu};
    const unsigned rot[2][4] = {{13u, 15u, 26u, 6u}, {17u, 29u, 16u, 24u}};
    x0 += ks[0]; x1 += ks[1];
#pragma unroll
    for (int i = 0; i < 5; i++) {
#pragma unroll
        for (int j = 0; j < 4; j++) {
            unsigned r = rot[i & 1][j];
            x0 += x1;
            x1 = (x1 << r) | (x1 >> (32 - r));
            x1 ^= x0;
        }
        x0 += ks[(i + 1) % 3];
        x1 += ks[(i + 2) % 3] + (unsigned)(i + 1);
    }
    o0 = x0; o1 = x1;
}

__device__ float gumbel_at(int j) {
    unsigned o0, o1;
    threefry2x32(0u, 42u, 0u, (unsigned)j, o0, o1);
    unsigned bits = o0 ^ o1;
    float f = __uint_as_float((bits >> 9) | 0x3F800000u) - 1.0f;  // [0,1)
    float u = fmaxf(f + 1.17549435e-38f, 1.17549435e-38f);
    return -logf(-logf(u));
}

// ---- encode, wave-per-(b,l): 4 waves/block each own one l; wave-private
// LDS window (25 rows x 9 ch); H=128 InstanceNorm via in-wave shfl_xor
// butterflies (2 h per lane). Only 2 barriers, no cross-wave reductions. ----
__global__ __launch_bounds__(256) void encode_kernel(
    const float* __restrict__ x_lt, const float* __restrict__ x_st,
    const float* __restrict__ Ws, const float* __restrict__ bs,
    const float* __restrict__ Wt, const float* __restrict__ bt,
    float* __restrict__ e_lt, float* __restrict__ e_st) {
    const int b = blockIdx.y;
    const int w = threadIdx.x >> 6, ln = threadIdx.x & 63;
    const float* x; float* e; int L, l;
    if (blockIdx.x < 128) { x = x_lt; e = e_lt; L = 512; l = blockIdx.x * 4 + w; }
    else { x = x_st; e = e_st; L = 128; l = (blockIdx.x - 128) * 4 + w; }
    __shared__ float xw_all[4][228];   // 225 window values per wave
    __shared__ float sm_all[4][20];    // seas[0..8], mm[10..18] per wave
    float* xw = xw_all[w];
    float* sm = sm_all[w];
    const float* xb = x + (size_t)b * L * 9;
#pragma unroll
    for (int q = 0; q < 4; q++) {
        int f = ln + 64 * q;
        if (f < 225) {
            int row = f / 9, c = f - row * 9;
            int rr = l - 12 + row;
            rr = rr < 0 ? 0 : (rr >= L ? L - 1 : rr);
            xw[f] = xb[(size_t)rr * 9 + c];
        }
    }
    __syncthreads();
    if (ln < 9) {
        float s = 0.f;
#pragma unroll
        for (int j = 0; j < 25; j++) s += xw[j * 9 + ln];
        float x0 = xb[ln];                       // x[b][0][c]
        float mm = (s - 25.f * x0) * (1.0f / 25.0f);
        sm[ln] = (xw[108 + ln] - x0) - mm;       // seas: x[l]-x0 - (mm-x0)
        sm[ln + 10] = mm;                        // trend input
    }
    __syncthreads();
    // each lane owns h = ln and h = ln+64
    float ysA = bs[ln], ysB = bs[ln + 64];
    float ytA = bt[ln], ytB = bt[ln + 64];
#pragma unroll
    for (int c = 0; c < 9; c++) {
        float sv = sm[c], mv = sm[c + 10];
        ysA += sv * Ws[c * 128 + ln];
        ysB += sv * Ws[c * 128 + ln + 64];
        ytA += mv * Wt[c * 128 + ln];
        ytB += mv * Wt[c * 128 + ln + 64];
    }
    float sa = ysA + ysB, sb2 = ytA + ytB;
#pragma unroll
    for (int off = 32; off > 0; off >>= 1) {
        sa += __shfl_xor(sa, off, 64);
        sb2 += __shfl_xor(sb2, off, 64);
    }
    float ms = sa * (1.0f / 128.0f), mt = sb2 * (1.0f / 128.0f);
    float dA = ysA - ms, dB = ysB - ms;
    float tA = ytA - mt, tB = ytB - mt;
    float qa = dA * dA + dB * dB, qb = tA * tA + tB * tB;
#pragma unroll
    for (int off = 32; off > 0; off >>= 1) {
        qa += __shfl_xor(qa, off, 64);
        qb += __shfl_xor(qb, off, 64);
    }
    float inva = rsqrtf(qa * (1.0f / 128.0f) + EPS);
    float invb = rsqrtf(qb * (1.0f / 128.0f) + EPS);
    float* eo = e + ((size_t)b * L + l) * 128;
    eo[ln] = gelu_exact(dA * inva) + gelu_exact(tA * invb);
    eo[ln + 64] = gelu_exact(dB * inva) + gelu_exact(tB * invb);
}

// ---- Linear -> InstanceNorm -> GELU with BLOCK-SHARED W chunks in LDS.
// Round-3 theory: per-wave W streaming is L2-BW-bound (each wave pulls the
// whole K*N*4B W; l1 alone = 128 MB/XCD-L2 ~= 30 us). Now each block stages
// W[KC][N] (32 KB) cooperatively once, 4 waves consume from LDS -> 4x less
// L2 traffic at IDENTICAL wave count (round-1 lesson: never trade occupancy
// for traffic here). TRANS tile overlays the W region after a barrier. ----
template <int K, int N, int WR, int KC, bool TRANS>
__global__ __launch_bounds__(256) void lbr_wave(
    const float* __restrict__ A, int S, int ABOFF,
    const float* __restrict__ W, const float* __restrict__ bias,
    float* __restrict__ out, int OROWS, int OBOFF) {
    constexpr int CG = N / 4;        // lanes covering the N dimension
    constexpr int SG = 64 / CG;      // row-subgroups per wave
    constexpr int RW = SG * WR;      // rows per wave
    constexpr int MT = 4 * RW;       // rows per block
    constexpr int LOG2MT = (MT == 8) ? 3 : ((MT == 16) ? 4 : 5);
    constexpr int WSZ = KC * N;      // shared W chunk (floats)
    constexpr int ASZ = 4 * RW * K;  // A stage, all 4 waves
    static_assert(WSZ >= MT * (N + 4), "TRANS tile must fit in W region");
    static_assert((WSZ / 4) % 256 == 0, "W chunk loads must be exact");
    __shared__ __align__(16) float lds[WSZ + ASZ];
    const int t = threadIdx.x;
    const int w = t >> 6, ln = t & 63;
    const int sg = ln / CG;
    const int n0 = (ln % CG) * 4;
    const int b = blockIdx.y;
    const int r0b = blockIdx.x * MT;
    const int r0w = r0b + w * RW;
    float* Wl = lds;
    float* As = lds + WSZ + w * RW * K;
    const float* Ab = A + (size_t)b * ABOFF;
    for (int idx = ln; idx < RW * (K / 4); idx += 64) {
        int rr = idx / (K / 4), kk = idx % (K / 4);
        float4 v = *(const float4*)(Ab + (size_t)(r0w + rr) * S + kk * 4);
        *(float4*)(As + rr * K + kk * 4) = v;
    }
    float4 acc[WR];
    {
        float4 bv = *(const float4*)(bias + n0);
#pragma unroll
        for (int j = 0; j < WR; j++) acc[j] = bv;
    }
    const float* ap = As + (sg * WR) * K;
    for (int kc0 = 0; kc0 < K; kc0 += KC) {
        __syncthreads();   // previous chunk fully consumed before overwrite
        {
            const float4* wg = (const float4*)(W + (size_t)kc0 * N);
            float4* wl4 = (float4*)Wl;
#pragma unroll
            for (int i = 0; i < WSZ / 4 / 256; i++)
                wl4[t + i * 256] = wg[t + i * 256];
        }
        __syncthreads();
#pragma unroll 2
        for (int k = 0; k < KC; k += 4) {
            const float* wp = Wl + k * N + n0;
            float4 w0 = *(const float4*)(wp);
            float4 w1 = *(const float4*)(wp + N);
            float4 w2 = *(const float4*)(wp + 2 * N);
            float4 w3 = *(const float4*)(wp + 3 * N);
#pragma unroll
            for (int j = 0; j < WR; j++) {
                float4 a4 = *(const float4*)(ap + j * K + kc0 + k);
                acc[j].x += a4.x * w0.x; acc[j].y += a4.x * w0.y;
                acc[j].z += a4.x * w0.z; acc[j].w += a4.x * w0.w;
                acc[j].x += a4.y * w1.x; acc[j].y += a4.y * w1.y;
                acc[j].z += a4.y * w1.z; acc[j].w += a4.y * w1.w;
                acc[j].x += a4.z * w2.x; acc[j].y += a4.z * w2.y;
                acc[j].z += a4.z * w2.z; acc[j].w += a4.z * w2.w;
                acc[j].x += a4.w * w3.x; acc[j].y += a4.w * w3.y;
                acc[j].z += a4.w * w3.z; acc[j].w += a4.w * w3.w;
            }
        }
    }
    float4 res[WR];
#pragma unroll
    for (int j = 0; j < WR; j++) {
        float s = acc[j].x + acc[j].y + acc[j].z + acc[j].w;
#pragma unroll
        for (int off = CG / 2; off > 0; off >>= 1) s += __shfl_xor(s, off, 64);
        float m = s * (1.0f / (float)N);
        float dx = acc[j].x - m, dy = acc[j].y - m, dz = acc[j].z - m, dw = acc[j].w - m;
        float q = dx * dx + dy * dy + dz * dz + dw * dw;
#pragma unroll
        for (int off = CG / 2; off > 0; off >>= 1) q += __shfl_xor(q, off, 64);
        float inv = rsqrtf(q * (1.0f / (float)N) + EPS);
        res[j].x = gelu_exact(dx * inv);
        res[j].y = gelu_exact(dy * inv);
        res[j].z = gelu_exact(dz * inv);
        res[j].w = gelu_exact(dw * inv);
    }
    if constexpr (TRANS) {
        __syncthreads();   // all waves done reading Wl -> safe to overlay
#pragma unroll
        for (int j = 0; j < WR; j++) {
            int rl = w * RW + sg * WR + j;
            *(float4*)(lds + rl * (N + 4) + n0) = res[j];
        }
        __syncthreads();
        float* ob = out + (size_t)b * OBOFF + r0b;
        for (int e = t; e < MT * N; e += 256) {
            int r = e & (MT - 1), n = e >> LOG2MT;
            ob[(size_t)n * OROWS + r] = lds[r * (N + 4) + n];
        }
    } else {
        float* ob = out + (size_t)b * OBOFF;
#pragma unroll
        for (int j = 0; j < WR; j++) {
            int row = r0w + sg * WR + j;
            *(float4*)(ob + (size_t)row * N + n0) = res[j];
        }
    }
}

// ---- fused logits + gumbel-softmax(hard) selection. grid 32 (b), block 256. ----
__global__ __launch_bounds__(256) void logits_select(
    const float* __restrict__ O6, const float* __restrict__ Wr,
    const float* __restrict__ br, float* __restrict__ sel_w, int* __restrict__ sel_r) {
    int b = blockIdx.x, t = threadIdx.x;
    __shared__ float sO6[128 * 68];
    __shared__ float red[4][8];
    const float4* ob4 = (const float4*)(O6 + (size_t)b * 8192);
    for (int i4 = t; i4 < 2048; i4 += 256) {
        float4 v = ob4[i4];
        int p = i4 * 4;
        int h = p >> 6, l4 = p & 63;
        *(float4*)(&sO6[h * 68 + l4]) = v;
    }
    __syncthreads();
    float acc[8] = {0, 0, 0, 0, 0, 0, 0, 0};
#pragma unroll 4
    for (int q = 0; q < 32; q++) {
        int i = q * 256 + t;  // logits flat index: l4 = i>>7, h = i&127
        int l4 = i >> 7, h = i & 127;
        float v = sO6[h * 68 + l4];
        const float4* wr = (const float4*)(Wr + (size_t)i * 8);
        float4 w0 = wr[0], w1 = wr[1];
        acc[0] += v * w0.x; acc[1] += v * w0.y; acc[2] += v * w0.z; acc[3] += v * w0.w;
        acc[4] += v * w1.x; acc[5] += v * w1.y; acc[6] += v * w1.z; acc[7] += v * w1.w;
    }
#pragma unroll
    for (int j = 0; j < 8; j++)
#pragma unroll
        for (int off = 32; off > 0; off >>= 1) acc[j] += __shfl_xor(acc[j], off, 64);
    int lane = t & 63, wid = t >> 6;
    if (lane == 0)
        for (int j = 0; j < 8; j++) red[wid][j] = acc[j];
    __syncthreads();
    if (t == 0) {
        float z[8];
        for (int j = 0; j < 8; j++) {
            float lg = br[j] + red[0][j] + red[1][j] + red[2][j] + red[3][j];
            z[j] = lg + gumbel_at(b * 8 + j);
        }
        int am = 0;
        float zm = z[0];
        for (int j = 1; j < 8; j++)
            if (z[j] > zm) { zm = z[j]; am = j; }
        float ssum = 0.f;
        for (int j = 0; j < 8; j++) ssum += expf(z[j] - zm);
        float s = 1.0f / ssum;
        sel_w[b] = (1.0f - s) + s;
        sel_r[b] = am;
    }
}

// ---- regime-grouped einsum v3: float4 proto reads, low VGPR, in-wave
// rowgroup reduce. grid (128 n, 8 r, 2 hz), block 192 (3 waves). ----
__global__ __launch_bounds__(192, 4) void einsum_nsplit(
    const float* __restrict__ e_st, const float* __restrict__ proto,
    const int* __restrict__ sel_r, float* __restrict__ part) {
    const int n = blockIdx.x, r = blockIdx.y, hz = blockIdx.z, t = threadIdx.x;
    const int w = t >> 6, ln = t & 63;
    const int rg = ln >> 4;             // rowgroup 0..3
    const int q4 = (w * 16 + (ln & 15)) * 4;  // float4 offset in 192-dim
    __shared__ int loc[32];
    __shared__ int s_gs;
    if (t == 0) {
        int g = 0;
        for (int bb = 0; bb < 32; bb++)
            if (sel_r[bb] == r) loc[g++] = bb;
        s_gs = g;
    }
    __syncthreads();
    const int gs = s_gs;
    if (gs == 0) return;
    __shared__ __align__(16) float es[64][12];  // [h_local][sb], 48B rows
    const float* pb = proto + (((size_t)r * 128 + n) * 128 + hz * 64) * 192;
    float* po = part + (size_t)hz * (32 * 128 * 192);
    for (int s0 = 0; s0 < gs; s0 += 8) {
        int np = gs - s0 < 8 ? gs - s0 : 8;
        __syncthreads();
        for (int i = t; i < 512; i += 192) {
            int sb = i >> 6, h = i & 63;
            float v = 0.f;
            if (sb < np)
                v = e_st[((size_t)loc[s0 + sb] * 128 + n) * 128 + hz * 64 + h];
            es[h][sb] = v;
        }
        __syncthreads();
        float4 a[8];
#pragma unroll
        for (int sb = 0; sb < 8; sb++) a[sb] = make_float4(0.f, 0.f, 0.f, 0.f);
#pragma unroll 4
        for (int hh = 0; hh < 16; hh++) {
            int row = hh * 4 + rg;
            float4 pv = *(const float4*)(pb + (size_t)row * 192 + q4);
            float4 e0 = *(const float4*)(&es[row][0]);
            float4 e1 = *(const float4*)(&es[row][4]);
#define ACC4(j, s) a[j].x += (s) * pv.x; a[j].y += (s) * pv.y; \
                   a[j].z += (s) * pv.z; a[j].w += (s) * pv.w;
            ACC4(0, e0.x) ACC4(1, e0.y) ACC4(2, e0.z) ACC4(3, e0.w)
            ACC4(4, e1.x) ACC4(5, e1.y) ACC4(6, e1.z) ACC4(7, e1.w)
#undef ACC4
        }
        // reduce across rowgroups (lanes ln, ln^16, ln^32 hold partials)
#pragma unroll
        for (int sb = 0; sb < 8; sb++) {
            a[sb].x += __shfl_xor(a[sb].x, 16, 64);
            a[sb].y += __shfl_xor(a[sb].y, 16, 64);
            a[sb].z += __shfl_xor(a[sb].z, 16, 64);
            a[sb].w += __shfl_xor(a[sb].w, 16, 64);
            a[sb].x += __shfl_xor(a[sb].x, 32, 64);
            a[sb].y += __shfl_xor(a[sb].y, 32, 64);
            a[sb].z += __shfl_xor(a[sb].z, 32, 64);
            a[sb].w += __shfl_xor(a[sb].w, 32, 64);
        }
        if (ln < 16) {
#pragma unroll
            for (int sb = 0; sb < 8; sb++) {
                if (sb < np) {
                    int bb = loc[s0 + sb];
                    *(float4*)(po + ((size_t)bb * 128 + n) * 192 + q4) = a[sb];
                }
            }
        }
    }
}

// ---- reduce 2x128 n-partials, scale by regime weight, softmax over 192 ----
__global__ void finalize_kernel(const float* __restrict__ part, const float* __restrict__ sel_w,
                                float* __restrict__ out) {
    int b = blockIdx.x, t = threadIdx.x;
    __shared__ float red[4];
    const float* p0 = part + (size_t)b * 128 * 192 + t;
    const float* p1 = p0 + (size_t)32 * 128 * 192;
    float v = 0.f;
#pragma unroll 8
    for (int c = 0; c < 128; c++) {
        v += p0[(size_t)c * 192];
        v += p1[(size_t)c * 192];
    }
    v *= sel_w[b];
    float mx = block_max(v, red);
    float e = expf(v - mx);
    float s = block_sum(e, red);
    out[(size_t)b * 192 + t] = e / s;
}

extern "C" void kernel_launch(void* const* d_in, const int* in_sizes, int n_in,
                              void* d_out, int out_size, void* d_ws, size_t ws_size,
                              hipStream_t stream) {
    const float* in_lt = (const float*)d_in[0];
    const float* in_st = (const float*)d_in[1];
    const float* Ws  = (const float*)d_in[2];  const float* bs  = (const float*)d_in[3];
    const float* Wt  = (const float*)d_in[4];  const float* bt  = (const float*)d_in[5];
    const float* Wh1 = (const float*)d_in[6];  const float* bh1 = (const float*)d_in[7];
    const float* Wl1 = (const float*)d_in[8];  const float* bl1 = (const float*)d_in[9];
    const float* Wh2 = (const float*)d_in[10]; const float* bh2 = (const float*)d_in[11];
    const float* Wl2 = (const float*)d_in[12]; const float* bl2 = (const float*)d_in[13];
    const float* Wh3 = (const float*)d_in[14]; const float* bh3 = (const float*)d_in[15];
    const float* Wl3 = (const float*)d_in[16]; const float* bl3 = (const float*)d_in[17];
    const float* Wr  = (const float*)d_in[18]; const float* br  = (const float*)d_in[19];
    const float* proto = (const float*)d_in[20];
    float* out = (float*)d_out;

    float* ws = (float*)d_ws;
    size_t off = 0;
    float* e_lt = ws + off; off += (size_t)32 * 512 * 128;   // [(b,l)][h]
    float* e_st = ws + off; off += (size_t)32 * 128 * 128;   // [b,n][h]
    float* O1T = ws + off; off += (size_t)128 * 16384;       // [h][(b,l)]
    float* O2T = ws + off; off += (size_t)256 * 4096;        // [l2][(b,h)]
    float* O3T = ws + off; off += (size_t)128 * 8192;        // [h][(b,l2)]
    float* O4T = ws + off; off += (size_t)128 * 4096;        // [l3][(b,h)]
    float* O5T = ws + off; off += (size_t)128 * 4096;        // [h][(b,l3)]
    float* O6 = ws + off; off += (size_t)32 * 128 * 64;      // [b][h][l4]
    float* part = ws + off; off += (size_t)2 * 32 * 128 * 192;  // [hz][b][n][t]
    float* sel_w = ws + off; off += 32;
    int* sel_r = (int*)(ws + off); off += 32;

    // encode: wave-per-(b,l), 4 l per block; lt chunks [0,128), st [128,160)
    encode_kernel<<<dim3(160, 32), 256, 0, stream>>>(in_lt, in_st, Ws, bs, Wt, bt, e_lt, e_st);
    // h1: flat 16384 rows, K=128, N=128; WR=2 (MT=16), KC=64, grid 1024
    lbr_wave<128, 128, 2, 64, true><<<dim3(1024, 1), 256, 0, stream>>>(
        e_lt, 128, 0, Wh1, bh1, O1T, 16384, 0);
    // l1: rows=h(128)/b, K=512, N=256; WR=2 (MT=8), KC=32 (16 chunks), grid 512
    lbr_wave<512, 256, 2, 32, true><<<dim3(16, 32), 256, 0, stream>>>(
        O1T, 16384, 512, Wl1, bl1, O2T, 4096, 128);
    // h2: rows=l2(256)/b, K=128, N=128; WR=2 (MT=16), KC=64, grid 512
    lbr_wave<128, 128, 2, 64, true><<<dim3(16, 32), 256, 0, stream>>>(
        O2T, 4096, 128, Wh2, bh2, O3T, 8192, 256);
    // l2: rows=h(128)/b, K=256, N=128; WR=1 (MT=8), KC=64 (4 chunks), grid 512
    lbr_wave<256, 128, 1, 64, true><<<dim3(16, 32), 256, 0, stream>>>(
        O3T, 8192, 256, Wl2, bl2, O4T, 4096, 128);
    // h3: rows=l3(128)/b, K=128, N=128; WR=1 (MT=8), KC=64, grid 512
    lbr_wave<128, 128, 1, 64, true><<<dim3(16, 32), 256, 0, stream>>>(
        O4T, 4096, 128, Wh3, bh3, O5T, 4096, 128);
    // l3: rows=h(128)/b, K=128, N=64; WR=1 (MT=16), KC=128 (whole W, 32 KB)
    lbr_wave<128, 64, 1, 128, false><<<dim3(8, 32), 256, 0, stream>>>(
        O5T, 4096, 128, Wl3, bl3, O6, 0, 8192);
    logits_select<<<32, 256, 0, stream>>>(O6, Wr, br, sel_w, sel_r);
    einsum_nsplit<<<dim3(128, 8, 2), 192, 0, stream>>>(e_st, proto, sel_r, part);
    finalize_kernel<<<32, 192, 0, stream>>>(part, sel_w, out);
}